// Round 2
// baseline (189.588 us; speedup 1.0000x reference)
//
#include <hip/hip_runtime.h>
#include <hip/hip_bf16.h>
#include <math.h>

// MoE top-2 of 8 experts. B=8, C=512, HW=1024, Dh=1024, E=8. fp32 in/out.
// R9: gemm1 rewritten as 256x256-tile, 512-thread, BK=64 counted-vmcnt pipeline
// (T3/T4-lite): 2-deep double-buffer, raw s_barrier, vmcnt(8) in steady state
// (never 0 until the tail) so prefetch loads span a full compute iteration.
// gemm2 / transpose / gate unchanged from R8 (XCD-aligned swizzles kept).
// Workspace (byte offsets):
//   0      tidx int[16];  64  scale fp32[16]
//   32768  xT  bf16 [8][1024 hw][512 c]
//   +8M    W1t bf16 [8][1024 d][512 c]
//   +16M   W2t bf16 [8][512 c][1024 d]
//   +24M   hT  bf16 [8][1024 hw][2048 slotd]  (pp fp32[8][16][512] aliases hT)

typedef __bf16 bf16_t;
typedef __attribute__((ext_vector_type(8))) __bf16 bf16x8;
typedef __attribute__((ext_vector_type(4))) __bf16 bf16x4;
typedef __attribute__((ext_vector_type(4))) float f32x4;

#define GLDS(g, l) __builtin_amdgcn_global_load_lds(                      \
    (const __attribute__((address_space(1))) void*)(const void*)(g),       \
    (__attribute__((address_space(3))) void*)(void*)(l), 16, 0, 0)

// bijective XCD-chunked swizzle (grid % 8 == 0): consecutive LOGICAL blocks
// share one XCD's L2.
__device__ __forceinline__ int xcd_swz(int bid, int grid) {
    return (bid & 7) * (grid >> 3) + (bid >> 3);
}

// erf via Abramowitz-Stegun 7.1.26 (validated R2..R8, absmax 0.031)
__device__ __forceinline__ float gelu_fast(float x) {
    float z = x * 0.70710678118654752f;
    float az = fabsf(z);
    float t = 1.0f / (1.0f + 0.3275911f * az);
    float p = ((((1.061405429f * t - 1.453152027f) * t + 1.421413741f) * t
                - 0.284496736f) * t + 0.254829592f) * t;
    float e = __expf(-az * az);
    float er = copysignf(1.0f - p * e, z);
    return 0.5f * x * (1.0f + er);
}

// ---------- 1. coalesced 64x64 transpose+cvt for x/W1/W2 + gate partials (R5-proven) ----------
__global__ __launch_bounds__(256) void transpose_cvt_all(
    const float* __restrict__ x, const float* __restrict__ W1,
    const float* __restrict__ W2, bf16_t* __restrict__ xT,
    bf16_t* __restrict__ W1t, bf16_t* __restrict__ W2t, float* __restrict__ pp) {
    int id = blockIdx.x;
    const float* src; bf16_t* dst; int Rows, Cols, csh; bool dm = false;
    if (id < 1024)      { src = x;  dst = xT;  Rows = 512;  Cols = 1024; csh = 4; dm = true; }
    else if (id < 2048) { id -= 1024; src = W1; dst = W1t; Rows = 512;  Cols = 1024; csh = 4; }
    else                { id -= 2048; src = W2; dst = W2t; Rows = 1024; Cols = 512; csh = 3; }
    const int bz = id >> 7, t = id & 127;
    const int ct = t & ((1 << csh) - 1), rt = t >> csh;
    const int r0 = rt * 64, c0 = ct * 64;
    __shared__ float tile[64][65];
    const int tid = threadIdx.x;
    const int lrw = tid >> 4, lcol = (tid & 15) * 4;
    const float* sb = src + (size_t)bz * Rows * Cols + c0;
    #pragma unroll
    for (int p = 0; p < 4; ++p) {
        const int row = p * 16 + lrw;
        float4 v = *(const float4*)(sb + (size_t)(r0 + row) * Cols + lcol);
        tile[row][lcol + 0] = v.x; tile[row][lcol + 1] = v.y;
        tile[row][lcol + 2] = v.z; tile[row][lcol + 3] = v.w;
    }
    __syncthreads();
    if (dm) {
        const int row = tid >> 2, q = tid & 3;
        float s = 0.f;
        #pragma unroll
        for (int j = 0; j < 16; ++j) s += tile[row][q * 16 + j];
        s += __shfl_down(s, 2, 4);
        s += __shfl_down(s, 1, 4);
        if (q == 0) pp[(bz * 16 + ct) * 512 + r0 + row] = s;
    }
    bf16_t* db = dst + (size_t)bz * Rows * Cols + r0;
    #pragma unroll
    for (int q = 0; q < 2; ++q) {
        const int idq = q * 256 + tid;
        const int orow = idq >> 3, seg = idq & 7;
        bf16_t ov[8];
        #pragma unroll
        for (int j = 0; j < 8; ++j) ov[j] = (bf16_t)tile[seg * 8 + j][orow];
        *(bf16x8*)(db + (size_t)(c0 + orow) * Rows + seg * 8) = *(bf16x8*)ov;
    }
}

// ---------- 2. gate: 8 blocks (one per sample) x 256 threads ----------
__global__ void gate_kernel(const float* __restrict__ pp, const float* __restrict__ Wg,
                            const float* __restrict__ bg, const float* __restrict__ kmod,
                            int* __restrict__ tidx, float* __restrict__ scale) {
    const int b = blockIdx.x;              // 8 blocks
    const int tid = threadIdx.x;           // 256 = 4 waves
    const int lane = tid & 63, wave = tid >> 6;
    float a[8] = {0.f, 0.f, 0.f, 0.f, 0.f, 0.f, 0.f, 0.f};
    #pragma unroll
    for (int rep = 0; rep < 2; ++rep) {
        const int c = rep * 256 + tid;
        float m = 0.f;
        #pragma unroll
        for (int ht = 0; ht < 16; ++ht) m += pp[(b * 16 + ht) * 512 + c];
        #pragma unroll
        for (int e = 0; e < 8; ++e) a[e] += m * Wg[c * 8 + e];
    }
    #pragma unroll
    for (int e = 0; e < 8; ++e)
        #pragma unroll
        for (int off = 32; off; off >>= 1) a[e] += __shfl_xor(a[e], off, 64);
    __shared__ float red[4][8];
    if (lane == 0) {
        #pragma unroll
        for (int e = 0; e < 8; ++e) red[wave][e] = a[e];
    }
    __syncthreads();
    if (tid == 0) {
        float lg[8], mx = -1e30f;
        #pragma unroll
        for (int e = 0; e < 8; ++e) {
            lg[e] = (red[0][e] + red[1][e] + red[2][e] + red[3][e]) * (1.0f / 1024.0f) + bg[e];
            mx = fmaxf(mx, lg[e]);
        }
        float sum = 0.f;
        #pragma unroll
        for (int e = 0; e < 8; ++e) { lg[e] = expf(lg[e] - mx); sum += lg[e]; }
        float inv = 1.0f / sum;
        float best = -1.f; int i0 = 0;
        for (int j = 0; j < 8; ++j) { float w = lg[j] * inv; if (w > best) { best = w; i0 = j; } }
        float best2 = -1.f; int i1 = 0;
        for (int j = 0; j < 8; ++j) { if (j == i0) continue; float w = lg[j] * inv; if (w > best2) { best2 = w; i1 = j; } }
        float kb = kmod[b];
        tidx[b * 2] = i0; tidx[b * 2 + 1] = i1;
        scale[b * 2] = best * kb; scale[b * 2 + 1] = best2 * kb;
    }
}

// ---------- 3. GEMM1: 256x256 tile, 512 thr (8 waves 2Mx4N), BK=64,
// 2-deep counted-vmcnt pipeline, raw barriers, XOR-swizzled LDS. ----------
// hT[b][hw][slot*1024+d] = bf16(gelu(W1t[e] @ xT[b] + b1) * scale)
// XCD swizzle: chunk of 32 blocks = pairs (2k,2k+1) -> XCD k writes hT[k].
__global__ __launch_bounds__(512, 2) void gemm1_kernel(
    const bf16_t* __restrict__ W1t, const bf16_t* __restrict__ xT,
    const float* __restrict__ b1, const int* __restrict__ tidx,
    const float* __restrict__ scale, bf16_t* __restrict__ hT) {
    // 128 KiB: A stages [0,16384),[16384,32768); B stages [32768,49152),[49152,65536)
    __shared__ bf16_t smem[65536];
    const int bid = xcd_swz(blockIdx.x, 256);
    const int pair = bid >> 4, rem = bid & 15;
    const int b = pair >> 1, slot = pair & 1;
    const int e = tidx[pair];
    const float s = scale[pair];
    const int d0 = (rem >> 2) * 256, n0 = (rem & 3) * 256;
    const int tid = threadIdx.x;
    const int lane = tid & 63, wave = tid >> 6;
    const int wrr = (wave >> 2) * 128;           // d offset within tile (2 M-waves)
    const int wcc = (wave & 3) * 64;             // hw offset within tile (4 N-waves)
    const int lrow = lane & 15, quad = lane >> 4;

    const bf16_t* gA = W1t + (size_t)e * 524288 + (size_t)d0 * 512;
    const bf16_t* gB = xT + (size_t)b * 524288 + (size_t)n0 * 512;

    f32x4 acc[8][4];
    #pragma unroll
    for (int i = 0; i < 8; ++i)
        #pragma unroll
        for (int j = 0; j < 4; ++j) acc[i][j] = (f32x4){0.f, 0.f, 0.f, 0.f};

    // stage one K-tile (A 256x64 + B 256x64) into stage st: 8 GLDS/thread
    auto stage = [&](int st, int kt) {
        const int k0 = kt * 64;
        bf16_t* As = smem + st * 16384;
        bf16_t* Bs = smem + 32768 + st * 16384;
        #pragma unroll
        for (int q = 0; q < 4; ++q) {
            const int idx = q * 512 + tid;        // 0..2047 16B-chunks
            const int row = idx >> 3;             // 0..255
            const int cg = ((idx & 7) ^ (row & 7)) * 8;
            GLDS(gA + (size_t)row * 512 + k0 + cg, As + idx * 8);
            GLDS(gB + (size_t)row * 512 + k0 + cg, Bs + idx * 8);
        }
    };

    auto compute = [&](int st) {
        const bf16_t* As = smem + st * 16384;
        const bf16_t* Bs = smem + 32768 + st * 16384;
        bf16x8 af[8][2], bf[4][2];
        #pragma unroll
        for (int m = 0; m < 8; ++m)
            #pragma unroll
            for (int kh = 0; kh < 2; ++kh)
                af[m][kh] = *(const bf16x8*)&As[(wrr + m * 16 + lrow) * 64
                                                + (((kh * 4 + quad) ^ (lrow & 7)) * 8)];
        #pragma unroll
        for (int n = 0; n < 4; ++n)
            #pragma unroll
            for (int kh = 0; kh < 2; ++kh)
                bf[n][kh] = *(const bf16x8*)&Bs[(wcc + n * 16 + lrow) * 64
                                                + (((kh * 4 + quad) ^ (lrow & 7)) * 8)];
        #pragma unroll
        for (int m = 0; m < 8; ++m)
            #pragma unroll
            for (int n = 0; n < 4; ++n)
                #pragma unroll
                for (int kh = 0; kh < 2; ++kh)
                    acc[m][n] = __builtin_amdgcn_mfma_f32_16x16x32_bf16(
                        af[m][kh], bf[n][kh], acc[m][n], 0, 0, 0);
    };

    // prologue: 2 K-tiles in flight
    stage(0, 0);
    stage(1, 1);
    asm volatile("s_waitcnt vmcnt(8)" ::: "memory");   // kt0 landed, kt1 in flight
    __builtin_amdgcn_s_barrier();

    #pragma unroll
    for (int kt = 0; kt < 8; ++kt) {
        const int cur = kt & 1;
        compute(cur);
        __builtin_amdgcn_s_barrier();                  // all waves done reading buf[cur]
        if (kt < 6) {
            stage(cur, kt + 2);                        // 8 loads join the queue
            asm volatile("s_waitcnt vmcnt(8)" ::: "memory");  // kt+1 landed, kt+2 in flight
        } else if (kt == 6) {
            asm volatile("s_waitcnt vmcnt(0)" ::: "memory");  // tail: drain kt7
        }
        __builtin_amdgcn_s_barrier();                  // buf[cur^1] ready for everyone
    }

    // epilogue: gelu*scale -> XOR-swizzled LDS [256 hw][256 d] -> coalesced 16B stores
    bf16_t* eb = smem;
    #pragma unroll
    for (int m = 0; m < 8; ++m) {
        const int d_l = wrr + m * 16 + quad * 4;
        const float4 bb = *(const float4*)(b1 + e * 1024 + d0 + d_l);
        #pragma unroll
        for (int n = 0; n < 4; ++n) {
            const int hw_l = wcc + n * 16 + lrow;
            f32x4 a = acc[m][n];
            bf16x4 o = { (bf16_t)(gelu_fast(a[0] + bb.x) * s),
                         (bf16_t)(gelu_fast(a[1] + bb.y) * s),
                         (bf16_t)(gelu_fast(a[2] + bb.z) * s),
                         (bf16_t)(gelu_fast(a[3] + bb.w) * s) };
            *(bf16x4*)&eb[hw_l * 256 + (d_l ^ ((hw_l & 7) << 3))] = o;
        }
    }
    __syncthreads();
    bf16_t* hTb = hT + (size_t)b * 2097152 + slot * 1024;
    #pragma unroll
    for (int q = 0; q < 16; ++q) {
        const int idx = q * 512 + tid;       // 8192 chunks = 256 rows x 32
        const int row = idx >> 5, c16 = idx & 31;
        bf16x8 v = *(const bf16x8*)&eb[row * 256 + ((c16 * 8) ^ ((row & 7) << 3))];
        *(bf16x8*)(hTb + (size_t)(n0 + row) * 2048 + d0 + c16 * 8) = v;
    }
}

// ---------- 4. GEMM2: operand-swapped (A=hT, B=W2t) -> D[hw][c]; c64 x hw128 tile,
// BK=64, dbuf, grid 512 (2 blk/CU). out = x + D + s0*b2[e0] + s1*b2[e1], float4 stores.
// XCD swizzle: logical chunk of 64 blocks = one b -> XCD b reads its own hT[b] (4MB = L2).
__global__ __launch_bounds__(256, 2) void gemm2_kernel(
    const bf16_t* __restrict__ W2t, const bf16_t* __restrict__ hT,
    const float* __restrict__ b2, const int* __restrict__ tidx,
    const float* __restrict__ scale, const float* __restrict__ x,
    float* __restrict__ out) {
    __shared__ bf16_t smem[24576];   // 2 stages x (A hT[128x64]@0 + B W2t[64x64]@8192)
    const int bid = xcd_swz(blockIdx.x, 512);
    const int b = bid >> 6, rem = bid & 63;      // grid = 8 * 64 = 512
    const int c0 = (rem >> 3) * 64, hw0 = (rem & 7) * 128;
    const int e0 = tidx[b * 2], e1 = tidx[b * 2 + 1];
    const float s0 = scale[b * 2], s1 = scale[b * 2 + 1];
    const int tid = threadIdx.x;
    const int lane = tid & 63, wave = tid >> 6;
    const int wm = (wave & 1) * 64;              // hw offset (M)
    const int wc = (wave >> 1) * 32;             // c offset (N)
    const int lrow = lane & 15, quad = lane >> 4;

    const bf16_t* hTb = hT + (size_t)b * 2097152 + (size_t)hw0 * 2048;
    const bf16_t* B0 = W2t + (size_t)e0 * 524288 + (size_t)c0 * 1024;
    const bf16_t* B1 = W2t + (size_t)e1 * 524288 + (size_t)c0 * 1024;

    f32x4 acc[4][2];
    #pragma unroll
    for (int i = 0; i < 4; ++i)
        #pragma unroll
        for (int j = 0; j < 2; ++j) acc[i][j] = (f32x4){0.f, 0.f, 0.f, 0.f};

    auto stage = [&](int st, int it) {
        const int k0 = it * 64;
        bf16_t* dst = smem + st * 12288;
        #pragma unroll
        for (int p = 0; p < 4; ++p) {            // A: hT 128 hw-rows
            const int row = p * 32 + (tid >> 3);
            const int cg = ((tid & 7) ^ (row & 7)) * 8;
            GLDS(hTb + (size_t)row * 2048 + k0 + cg, dst + (p * 256 + tid) * 8);
        }
        const bf16_t* gB = ((it < 16) ? B0 : B1) + (k0 & 1023);
        #pragma unroll
        for (int p = 0; p < 2; ++p) {            // B: W2t 64 c-rows
            const int row = p * 32 + (tid >> 3);
            const int cg = ((tid & 7) ^ (row & 7)) * 8;
            GLDS(gB + (size_t)row * 1024 + cg, dst + 8192 + (p * 256 + tid) * 8);
        }
    };

    stage(0, 0);
    __syncthreads();

    for (int it = 0; it < 32; ++it) {
        const int cur = it & 1;
        if (it < 31) stage(cur ^ 1, it + 1);
        const bf16_t* cA = smem + cur * 12288;
        const bf16_t* cB = cA + 8192;
        #pragma unroll
        for (int kh = 0; kh < 2; ++kh) {
            const int swz = ((kh * 4 + quad) ^ (lrow & 7)) * 8;
            bf16x8 af[4], bfr[2];
            #pragma unroll
            for (int i = 0; i < 4; ++i)
                af[i] = *(const bf16x8*)&cA[(wm + i * 16 + lrow) * 64 + swz];
            #pragma unroll
            for (int j = 0; j < 2; ++j)
                bfr[j] = *(const bf16x8*)&cB[(wc + j * 16 + lrow) * 64 + swz];
            #pragma unroll
            for (int i = 0; i < 4; ++i)
                #pragma unroll
                for (int j = 0; j < 2; ++j)
                    acc[i][j] = __builtin_amdgcn_mfma_f32_16x16x32_bf16(af[i], bfr[j], acc[i][j], 0, 0, 0);
        }
        __syncthreads();
    }

    // epilogue: lane f32x4 = 4 consecutive hw at one c -> fully-coalesced float4
    #pragma unroll
    for (int j = 0; j < 2; ++j) {
        const int c = c0 + wc + j * 16 + lrow;
        const float bias = s0 * b2[e0 * 512 + c] + s1 * b2[e1 * 512 + c];
        #pragma unroll
        for (int i = 0; i < 4; ++i) {
            const int hw = hw0 + wm + i * 16 + quad * 4;
            const size_t o = ((size_t)(b * 512 + c)) * 1024 + hw;
            const float4 xv = *(const float4*)(x + o);
            float4 ov = { acc[i][j][0] + xv.x + bias, acc[i][j][1] + xv.y + bias,
                          acc[i][j][2] + xv.z + bias, acc[i][j][3] + xv.w + bias };
            *(float4*)(out + o) = ov;
        }
    }
}

extern "C" void kernel_launch(void* const* d_in, const int* in_sizes, int n_in,
                              void* d_out, int out_size, void* d_ws, size_t ws_size,
                              hipStream_t stream) {
    const float* x    = (const float*)d_in[0];
    const float* kmod = (const float*)d_in[1];
    const float* Wg   = (const float*)d_in[2];
    const float* bg   = (const float*)d_in[3];
    const float* W1   = (const float*)d_in[4];
    const float* b1   = (const float*)d_in[5];
    const float* W2   = (const float*)d_in[6];
    const float* b2   = (const float*)d_in[7];
    float* out = (float*)d_out;

    char* ws = (char*)d_ws;
    int*   tix  = (int*)ws;
    float* scl  = (float*)(ws + 64);
    bf16_t* xT  = (bf16_t*)(ws + 32768);
    bf16_t* W1t = (bf16_t*)(ws + 32768 + (size_t)8388608);
    bf16_t* W2t = (bf16_t*)(ws + 32768 + (size_t)2 * 8388608);
    bf16_t* hT  = (bf16_t*)(ws + 32768 + (size_t)3 * 8388608);
    float* pp   = (float*)hT;   // gate partials; dead before gemm1 writes hT

    transpose_cvt_all<<<3072, 256, 0, stream>>>(x, W1, W2, xT, W1t, W2t, pp);
    gate_kernel<<<8, 256, 0, stream>>>(pp, Wg, bg, kmod, tix, scl);
    gemm1_kernel<<<256, 512, 0, stream>>>(W1t, xT, b1, tix, scl, hT);    // 16 pairs x 16
    gemm2_kernel<<<512, 256, 0, stream>>>(W2t, hT, b2, tix, scl, x, out); // 8 x 64
}

// Round 3
// 164.449 us; speedup vs baseline: 1.1529x; 1.1529x over previous
//
#include <hip/hip_runtime.h>
#include <hip/hip_bf16.h>
#include <math.h>

// MoE top-2 of 8 experts. B=8, C=512, HW=1024, Dh=1024, E=8. fp32 in/out.
// R10: gemm1 REVERTED to R8-proven 128x128 / 4-blk/CU structure (R9's 256x256
// 1-blk/CU counted-vmcnt regressed: MfmaUtil 10%, 1.9 TB/s). gemm2 keeps its
// exact tile/occupancy/dbuf but swaps drain-per-step __syncthreads for a 2-deep
// counted-vmcnt schedule (vmcnt(6) steady state, vmcnt(0) only at tail) —
// isolates the T4 variable. x residual prefetched to registers pre-loop.
// Workspace (byte offsets):
//   0      tidx int[16];  64  scale fp32[16]
//   32768  xT  bf16 [8][1024 hw][512 c]
//   +8M    W1t bf16 [8][1024 d][512 c]
//   +16M   W2t bf16 [8][512 c][1024 d]
//   +24M   hT  bf16 [8][1024 hw][2048 slotd]  (pp fp32[8][16][512] aliases hT)

typedef __bf16 bf16_t;
typedef __attribute__((ext_vector_type(8))) __bf16 bf16x8;
typedef __attribute__((ext_vector_type(4))) __bf16 bf16x4;
typedef __attribute__((ext_vector_type(4))) float f32x4;

#define GLDS(g, l) __builtin_amdgcn_global_load_lds(                      \
    (const __attribute__((address_space(1))) void*)(const void*)(g),       \
    (__attribute__((address_space(3))) void*)(void*)(l), 16, 0, 0)

// bijective XCD-chunked swizzle (grid % 8 == 0): consecutive LOGICAL blocks
// share one XCD's L2.
__device__ __forceinline__ int xcd_swz(int bid, int grid) {
    return (bid & 7) * (grid >> 3) + (bid >> 3);
}

// erf via Abramowitz-Stegun 7.1.26 (validated R2..R9, absmax 0.031)
__device__ __forceinline__ float gelu_fast(float x) {
    float z = x * 0.70710678118654752f;
    float az = fabsf(z);
    float t = 1.0f / (1.0f + 0.3275911f * az);
    float p = ((((1.061405429f * t - 1.453152027f) * t + 1.421413741f) * t
                - 0.284496736f) * t + 0.254829592f) * t;
    float e = __expf(-az * az);
    float er = copysignf(1.0f - p * e, z);
    return 0.5f * x * (1.0f + er);
}

// ---------- 1. coalesced 64x64 transpose+cvt for x/W1/W2 + gate partials (R5-proven) ----------
__global__ __launch_bounds__(256) void transpose_cvt_all(
    const float* __restrict__ x, const float* __restrict__ W1,
    const float* __restrict__ W2, bf16_t* __restrict__ xT,
    bf16_t* __restrict__ W1t, bf16_t* __restrict__ W2t, float* __restrict__ pp) {
    int id = blockIdx.x;
    const float* src; bf16_t* dst; int Rows, Cols, csh; bool dm = false;
    if (id < 1024)      { src = x;  dst = xT;  Rows = 512;  Cols = 1024; csh = 4; dm = true; }
    else if (id < 2048) { id -= 1024; src = W1; dst = W1t; Rows = 512;  Cols = 1024; csh = 4; }
    else                { id -= 2048; src = W2; dst = W2t; Rows = 1024; Cols = 512; csh = 3; }
    const int bz = id >> 7, t = id & 127;
    const int ct = t & ((1 << csh) - 1), rt = t >> csh;
    const int r0 = rt * 64, c0 = ct * 64;
    __shared__ float tile[64][65];
    const int tid = threadIdx.x;
    const int lrw = tid >> 4, lcol = (tid & 15) * 4;
    const float* sb = src + (size_t)bz * Rows * Cols + c0;
    #pragma unroll
    for (int p = 0; p < 4; ++p) {
        const int row = p * 16 + lrw;
        float4 v = *(const float4*)(sb + (size_t)(r0 + row) * Cols + lcol);
        tile[row][lcol + 0] = v.x; tile[row][lcol + 1] = v.y;
        tile[row][lcol + 2] = v.z; tile[row][lcol + 3] = v.w;
    }
    __syncthreads();
    if (dm) {
        const int row = tid >> 2, q = tid & 3;
        float s = 0.f;
        #pragma unroll
        for (int j = 0; j < 16; ++j) s += tile[row][q * 16 + j];
        s += __shfl_down(s, 2, 4);
        s += __shfl_down(s, 1, 4);
        if (q == 0) pp[(bz * 16 + ct) * 512 + r0 + row] = s;
    }
    bf16_t* db = dst + (size_t)bz * Rows * Cols + r0;
    #pragma unroll
    for (int q = 0; q < 2; ++q) {
        const int idq = q * 256 + tid;
        const int orow = idq >> 3, seg = idq & 7;
        bf16_t ov[8];
        #pragma unroll
        for (int j = 0; j < 8; ++j) ov[j] = (bf16_t)tile[seg * 8 + j][orow];
        *(bf16x8*)(db + (size_t)(c0 + orow) * Rows + seg * 8) = *(bf16x8*)ov;
    }
}

// ---------- 2. gate: 8 blocks (one per sample) x 256 threads ----------
__global__ void gate_kernel(const float* __restrict__ pp, const float* __restrict__ Wg,
                            const float* __restrict__ bg, const float* __restrict__ kmod,
                            int* __restrict__ tidx, float* __restrict__ scale) {
    const int b = blockIdx.x;              // 8 blocks
    const int tid = threadIdx.x;           // 256 = 4 waves
    const int lane = tid & 63, wave = tid >> 6;
    float a[8] = {0.f, 0.f, 0.f, 0.f, 0.f, 0.f, 0.f, 0.f};
    #pragma unroll
    for (int rep = 0; rep < 2; ++rep) {
        const int c = rep * 256 + tid;
        float m = 0.f;
        #pragma unroll
        for (int ht = 0; ht < 16; ++ht) m += pp[(b * 16 + ht) * 512 + c];
        #pragma unroll
        for (int e = 0; e < 8; ++e) a[e] += m * Wg[c * 8 + e];
    }
    #pragma unroll
    for (int e = 0; e < 8; ++e)
        #pragma unroll
        for (int off = 32; off; off >>= 1) a[e] += __shfl_xor(a[e], off, 64);
    __shared__ float red[4][8];
    if (lane == 0) {
        #pragma unroll
        for (int e = 0; e < 8; ++e) red[wave][e] = a[e];
    }
    __syncthreads();
    if (tid == 0) {
        float lg[8], mx = -1e30f;
        #pragma unroll
        for (int e = 0; e < 8; ++e) {
            lg[e] = (red[0][e] + red[1][e] + red[2][e] + red[3][e]) * (1.0f / 1024.0f) + bg[e];
            mx = fmaxf(mx, lg[e]);
        }
        float sum = 0.f;
        #pragma unroll
        for (int e = 0; e < 8; ++e) { lg[e] = expf(lg[e] - mx); sum += lg[e]; }
        float inv = 1.0f / sum;
        float best = -1.f; int i0 = 0;
        for (int j = 0; j < 8; ++j) { float w = lg[j] * inv; if (w > best) { best = w; i0 = j; } }
        float best2 = -1.f; int i1 = 0;
        for (int j = 0; j < 8; ++j) { if (j == i0) continue; float w = lg[j] * inv; if (w > best2) { best2 = w; i1 = j; } }
        float kb = kmod[b];
        tidx[b * 2] = i0; tidx[b * 2 + 1] = i1;
        scale[b * 2] = best * kb; scale[b * 2 + 1] = best2 * kb;
    }
}

// ---------- 3. GEMM1: 128x128 tile, BK=64, single-buffer, XOR-swizzled LDS (R8-proven) ----------
// hT[b][hw][slot*1024+d] = bf16(gelu(W1t[e] @ xT[b] + b1) * scale)
// XCD swizzle: logical chunk of 128 blocks = pairs (2b,2b+1) -> XCD b writes hT[b].
__global__ __launch_bounds__(256, 4) void gemm1_kernel(
    const bf16_t* __restrict__ W1t, const bf16_t* __restrict__ xT,
    const float* __restrict__ b1, const int* __restrict__ tidx,
    const float* __restrict__ scale, bf16_t* __restrict__ hT) {
    __shared__ bf16_t smem[17408];   // stage: A[128x64]@0, B[128x64]@8192; ebuf 128x136
    const int bid = xcd_swz(blockIdx.x, 1024);
    const int pair = bid >> 6, rem = bid & 63;
    const int b = pair >> 1, slot = pair & 1;
    const int e = tidx[pair];
    const float s = scale[pair];
    const int d0 = (rem >> 3) * 128, n0 = (rem & 7) * 128;
    const int tid = threadIdx.x;
    const int lane = tid & 63, wave = tid >> 6;
    const int wm = (wave & 1) * 64, wn = (wave >> 1) * 64;
    const int lrow = lane & 15, quad = lane >> 4;

    const bf16_t* gA = W1t + (size_t)e * 524288 + (size_t)d0 * 512;
    const bf16_t* gB = xT + (size_t)b * 524288 + (size_t)n0 * 512;

    f32x4 acc[4][4];
    #pragma unroll
    for (int i = 0; i < 4; ++i)
        #pragma unroll
        for (int j = 0; j < 4; ++j) acc[i][j] = (f32x4){0.f, 0.f, 0.f, 0.f};

    for (int it = 0; it < 8; ++it) {
        const int k0 = it * 64;
        // stage: 8 lanes x 16B = full 128B line per row; XOR-swizzle chunk placement
        #pragma unroll
        for (int p = 0; p < 4; ++p) {
            const int row = p * 32 + (tid >> 3);
            const int cg = ((tid & 7) ^ (row & 7)) * 8;
            GLDS(gA + (size_t)row * 512 + k0 + cg, smem + (p * 256 + tid) * 8);
            GLDS(gB + (size_t)row * 512 + k0 + cg, smem + 8192 + (p * 256 + tid) * 8);
        }
        __syncthreads();
        #pragma unroll
        for (int kh = 0; kh < 2; ++kh) {
            const int swz = ((kh * 4 + quad) ^ (lrow & 7)) * 8;
            bf16x8 af[4], bfr[4];
            #pragma unroll
            for (int i = 0; i < 4; ++i) {
                af[i]  = *(const bf16x8*)&smem[(wm + i * 16 + lrow) * 64 + swz];
                bfr[i] = *(const bf16x8*)&smem[8192 + (wn + i * 16 + lrow) * 64 + swz];
            }
            #pragma unroll
            for (int i = 0; i < 4; ++i)
                #pragma unroll
                for (int j = 0; j < 4; ++j)
                    acc[i][j] = __builtin_amdgcn_mfma_f32_16x16x32_bf16(af[i], bfr[j], acc[i][j], 0, 0, 0);
        }
        __syncthreads();
    }

    // epilogue: all waves write all frags (one barrier), then coalesced 16B stores
    bf16_t* hTb = hT + (size_t)b * 2097152 + slot * 1024;
    #pragma unroll
    for (int i = 0; i < 4; ++i) {
        const int d_l = wm + i * 16 + quad * 4;
        const float4 bb = *(const float4*)(b1 + e * 1024 + d0 + d_l);
        #pragma unroll
        for (int j = 0; j < 4; ++j) {
            const int hw_l = wn + j * 16 + lrow;
            f32x4 a = acc[i][j];
            bf16x4 o = { (bf16_t)(gelu_fast(a[0] + bb.x) * s),
                         (bf16_t)(gelu_fast(a[1] + bb.y) * s),
                         (bf16_t)(gelu_fast(a[2] + bb.z) * s),
                         (bf16_t)(gelu_fast(a[3] + bb.w) * s) };
            *(bf16x4*)&smem[hw_l * 136 + d_l] = o;
        }
    }
    __syncthreads();
    #pragma unroll
    for (int q = 0; q < 8; ++q) {
        const int idx = q * 256 + tid;       // 2048 chunks = 128 rows x 16
        const int row = idx >> 4, c16 = idx & 15;
        bf16x8 v = *(const bf16x8*)&smem[row * 136 + c16 * 8];
        *(bf16x8*)(hTb + (size_t)(n0 + row) * 2048 + d0 + c16 * 8) = v;
    }
}

// ---------- 4. GEMM2: operand-swapped (A=hT, B=W2t) -> D[hw][c]; c64 x hw128 tile,
// BK=64, dbuf, grid 512 (2 blk/CU). out = x + D + s0*b2[e0] + s1*b2[e1], float4 stores.
// R10: 2-deep counted-vmcnt schedule (tile/occupancy/LDS unchanged vs R8):
// vmcnt(6) steady state so the next tile's 6 loads stay in flight across both
// barriers; vmcnt(0) only at it=31. x residual prefetched to regs pre-loop.
__global__ __launch_bounds__(256, 2) void gemm2_kernel(
    const bf16_t* __restrict__ W2t, const bf16_t* __restrict__ hT,
    const float* __restrict__ b2, const int* __restrict__ tidx,
    const float* __restrict__ scale, const float* __restrict__ x,
    float* __restrict__ out) {
    __shared__ bf16_t smem[24576];   // 2 stages x (A hT[128x64]@0 + B W2t[64x64]@8192)
    const int bid = xcd_swz(blockIdx.x, 512);
    const int b = bid >> 6, rem = bid & 63;      // grid = 8 * 64 = 512
    const int c0 = (rem >> 3) * 64, hw0 = (rem & 7) * 128;
    const int e0 = tidx[b * 2], e1 = tidx[b * 2 + 1];
    const float s0 = scale[b * 2], s1 = scale[b * 2 + 1];
    const int tid = threadIdx.x;
    const int lane = tid & 63, wave = tid >> 6;
    const int wm = (wave & 1) * 64;              // hw offset (M)
    const int wc = (wave >> 1) * 32;             // c offset (N)
    const int lrow = lane & 15, quad = lane >> 4;

    const bf16_t* hTb = hT + (size_t)b * 2097152 + (size_t)hw0 * 2048;
    const bf16_t* B0 = W2t + (size_t)e0 * 524288 + (size_t)c0 * 1024;
    const bf16_t* B1 = W2t + (size_t)e1 * 524288 + (size_t)c0 * 1024;

    // prefetch residual x: 8 float4/thread (issued before any vmcnt asm, so
    // they drain with tile-0's wait; hides the old serial epilogue tail)
    float4 xr[2][4];
    #pragma unroll
    for (int j = 0; j < 2; ++j) {
        const int c = c0 + wc + j * 16 + lrow;
        #pragma unroll
        for (int i = 0; i < 4; ++i) {
            const int hw = hw0 + wm + i * 16 + quad * 4;
            xr[j][i] = *(const float4*)(x + ((size_t)(b * 512 + c)) * 1024 + hw);
        }
    }

    f32x4 acc[4][2];
    #pragma unroll
    for (int i = 0; i < 4; ++i)
        #pragma unroll
        for (int j = 0; j < 2; ++j) acc[i][j] = (f32x4){0.f, 0.f, 0.f, 0.f};

    auto stage = [&](int st, int it) {           // 6 GLDS / thread
        const int k0 = it * 64;
        bf16_t* dst = smem + st * 12288;
        #pragma unroll
        for (int p = 0; p < 4; ++p) {            // A: hT 128 hw-rows
            const int row = p * 32 + (tid >> 3);
            const int cg = ((tid & 7) ^ (row & 7)) * 8;
            GLDS(hTb + (size_t)row * 2048 + k0 + cg, dst + (p * 256 + tid) * 8);
        }
        const bf16_t* gB = ((it < 16) ? B0 : B1) + (k0 & 1023);
        #pragma unroll
        for (int p = 0; p < 2; ++p) {            // B: W2t 64 c-rows
            const int row = p * 32 + (tid >> 3);
            const int cg = ((tid & 7) ^ (row & 7)) * 8;
            GLDS(gB + (size_t)row * 1024 + cg, dst + 8192 + (p * 256 + tid) * 8);
        }
    };

    // prologue: 2 tiles in flight (12 outstanding loads + 8 x-prefetch)
    stage(0, 0);
    stage(1, 1);

    for (int it = 0; it < 32; ++it) {
        const int cur = it & 1;
        if (it < 31) {
            asm volatile("s_waitcnt vmcnt(6)" ::: "memory");   // tile it landed; it+1 in flight
        } else {
            asm volatile("s_waitcnt vmcnt(0)" ::: "memory");   // tail: drain tile 31
        }
        __builtin_amdgcn_s_barrier();            // all waves' tile-it slices in LDS
        const bf16_t* cA = smem + cur * 12288;
        const bf16_t* cB = cA + 8192;
        #pragma unroll
        for (int kh = 0; kh < 2; ++kh) {
            const int swz = ((kh * 4 + quad) ^ (lrow & 7)) * 8;
            bf16x8 af[4], bfr[2];
            #pragma unroll
            for (int i = 0; i < 4; ++i)
                af[i] = *(const bf16x8*)&cA[(wm + i * 16 + lrow) * 64 + swz];
            #pragma unroll
            for (int j = 0; j < 2; ++j)
                bfr[j] = *(const bf16x8*)&cB[(wc + j * 16 + lrow) * 64 + swz];
            #pragma unroll
            for (int i = 0; i < 4; ++i)
                #pragma unroll
                for (int j = 0; j < 2; ++j)
                    acc[i][j] = __builtin_amdgcn_mfma_f32_16x16x32_bf16(af[i], bfr[j], acc[i][j], 0, 0, 0);
        }
        __builtin_amdgcn_s_barrier();            // all waves done reading buf[cur]
        if (it < 30) stage(cur, it + 2);         // overwrite buf[cur] for tile it+2
    }

    // epilogue: lane f32x4 = 4 consecutive hw at one c -> fully-coalesced float4
    #pragma unroll
    for (int j = 0; j < 2; ++j) {
        const int c = c0 + wc + j * 16 + lrow;
        const float bias = s0 * b2[e0 * 512 + c] + s1 * b2[e1 * 512 + c];
        #pragma unroll
        for (int i = 0; i < 4; ++i) {
            const int hw = hw0 + wm + i * 16 + quad * 4;
            const size_t o = ((size_t)(b * 512 + c)) * 1024 + hw;
            const float4 xv = xr[j][i];
            float4 ov = { acc[i][j][0] + xv.x + bias, acc[i][j][1] + xv.y + bias,
                          acc[i][j][2] + xv.z + bias, acc[i][j][3] + xv.w + bias };
            *(float4*)(out + o) = ov;
        }
    }
}

extern "C" void kernel_launch(void* const* d_in, const int* in_sizes, int n_in,
                              void* d_out, int out_size, void* d_ws, size_t ws_size,
                              hipStream_t stream) {
    const float* x    = (const float*)d_in[0];
    const float* kmod = (const float*)d_in[1];
    const float* Wg   = (const float*)d_in[2];
    const float* bg   = (const float*)d_in[3];
    const float* W1   = (const float*)d_in[4];
    const float* b1   = (const float*)d_in[5];
    const float* W2   = (const float*)d_in[6];
    const float* b2   = (const float*)d_in[7];
    float* out = (float*)d_out;

    char* ws = (char*)d_ws;
    int*   tix  = (int*)ws;
    float* scl  = (float*)(ws + 64);
    bf16_t* xT  = (bf16_t*)(ws + 32768);
    bf16_t* W1t = (bf16_t*)(ws + 32768 + (size_t)8388608);
    bf16_t* W2t = (bf16_t*)(ws + 32768 + (size_t)2 * 8388608);
    bf16_t* hT  = (bf16_t*)(ws + 32768 + (size_t)3 * 8388608);
    float* pp   = (float*)hT;   // gate partials; dead before gemm1 writes hT

    transpose_cvt_all<<<3072, 256, 0, stream>>>(x, W1, W2, xT, W1t, W2t, pp);
    gate_kernel<<<8, 256, 0, stream>>>(pp, Wg, bg, kmod, tix, scl);
    gemm1_kernel<<<1024, 256, 0, stream>>>(W1t, xT, b1, tix, scl, hT);   // 16 pairs x 64
    gemm2_kernel<<<512, 256, 0, stream>>>(W2t, hT, b2, tix, scl, x, out); // 8 x 64
}

// Round 4
// 159.863 us; speedup vs baseline: 1.1859x; 1.0287x over previous
//
#include <hip/hip_runtime.h>
#include <hip/hip_bf16.h>
#include <math.h>

// MoE top-2 of 8 experts. B=8, C=512, HW=1024, Dh=1024, E=8. fp32 in/out.
// R11: gemm1 gets the R10-proven minimal T4 transform: SAME 128x128 tile /
// 256 thr / stage / frag / epilogue, but double-buffered (LDS 34->64 KiB,
// 2 blk/CU) with 2-deep counted-vmcnt (vmcnt(8) steady, vmcnt(0) tail only).
// Two independent 4-wave blocks/CU keep m114 overlap (unlike R9's 8-wave block).
// gemm2 = R10 counted-vmcnt version (proven -6us). transpose/gate unchanged.
// Workspace (byte offsets):
//   0      tidx int[16];  64  scale fp32[16]
//   32768  xT  bf16 [8][1024 hw][512 c]
//   +8M    W1t bf16 [8][1024 d][512 c]
//   +16M   W2t bf16 [8][512 c][1024 d]
//   +24M   hT  bf16 [8][1024 hw][2048 slotd]  (pp fp32[8][16][512] aliases hT)

typedef __bf16 bf16_t;
typedef __attribute__((ext_vector_type(8))) __bf16 bf16x8;
typedef __attribute__((ext_vector_type(4))) __bf16 bf16x4;
typedef __attribute__((ext_vector_type(4))) float f32x4;

#define GLDS(g, l) __builtin_amdgcn_global_load_lds(                      \
    (const __attribute__((address_space(1))) void*)(const void*)(g),       \
    (__attribute__((address_space(3))) void*)(void*)(l), 16, 0, 0)

// bijective XCD-chunked swizzle (grid % 8 == 0): consecutive LOGICAL blocks
// share one XCD's L2.
__device__ __forceinline__ int xcd_swz(int bid, int grid) {
    return (bid & 7) * (grid >> 3) + (bid >> 3);
}

// erf via Abramowitz-Stegun 7.1.26 (validated R2..R10, absmax 0.031)
__device__ __forceinline__ float gelu_fast(float x) {
    float z = x * 0.70710678118654752f;
    float az = fabsf(z);
    float t = 1.0f / (1.0f + 0.3275911f * az);
    float p = ((((1.061405429f * t - 1.453152027f) * t + 1.421413741f) * t
                - 0.284496736f) * t + 0.254829592f) * t;
    float e = __expf(-az * az);
    float er = copysignf(1.0f - p * e, z);
    return 0.5f * x * (1.0f + er);
}

// ---------- 1. coalesced 64x64 transpose+cvt for x/W1/W2 + gate partials (R5-proven) ----------
__global__ __launch_bounds__(256) void transpose_cvt_all(
    const float* __restrict__ x, const float* __restrict__ W1,
    const float* __restrict__ W2, bf16_t* __restrict__ xT,
    bf16_t* __restrict__ W1t, bf16_t* __restrict__ W2t, float* __restrict__ pp) {
    int id = blockIdx.x;
    const float* src; bf16_t* dst; int Rows, Cols, csh; bool dm = false;
    if (id < 1024)      { src = x;  dst = xT;  Rows = 512;  Cols = 1024; csh = 4; dm = true; }
    else if (id < 2048) { id -= 1024; src = W1; dst = W1t; Rows = 512;  Cols = 1024; csh = 4; }
    else                { id -= 2048; src = W2; dst = W2t; Rows = 1024; Cols = 512; csh = 3; }
    const int bz = id >> 7, t = id & 127;
    const int ct = t & ((1 << csh) - 1), rt = t >> csh;
    const int r0 = rt * 64, c0 = ct * 64;
    __shared__ float tile[64][65];
    const int tid = threadIdx.x;
    const int lrw = tid >> 4, lcol = (tid & 15) * 4;
    const float* sb = src + (size_t)bz * Rows * Cols + c0;
    #pragma unroll
    for (int p = 0; p < 4; ++p) {
        const int row = p * 16 + lrw;
        float4 v = *(const float4*)(sb + (size_t)(r0 + row) * Cols + lcol);
        tile[row][lcol + 0] = v.x; tile[row][lcol + 1] = v.y;
        tile[row][lcol + 2] = v.z; tile[row][lcol + 3] = v.w;
    }
    __syncthreads();
    if (dm) {
        const int row = tid >> 2, q = tid & 3;
        float s = 0.f;
        #pragma unroll
        for (int j = 0; j < 16; ++j) s += tile[row][q * 16 + j];
        s += __shfl_down(s, 2, 4);
        s += __shfl_down(s, 1, 4);
        if (q == 0) pp[(bz * 16 + ct) * 512 + r0 + row] = s;
    }
    bf16_t* db = dst + (size_t)bz * Rows * Cols + r0;
    #pragma unroll
    for (int q = 0; q < 2; ++q) {
        const int idq = q * 256 + tid;
        const int orow = idq >> 3, seg = idq & 7;
        bf16_t ov[8];
        #pragma unroll
        for (int j = 0; j < 8; ++j) ov[j] = (bf16_t)tile[seg * 8 + j][orow];
        *(bf16x8*)(db + (size_t)(c0 + orow) * Rows + seg * 8) = *(bf16x8*)ov;
    }
}

// ---------- 2. gate: 8 blocks (one per sample) x 256 threads ----------
__global__ void gate_kernel(const float* __restrict__ pp, const float* __restrict__ Wg,
                            const float* __restrict__ bg, const float* __restrict__ kmod,
                            int* __restrict__ tidx, float* __restrict__ scale) {
    const int b = blockIdx.x;              // 8 blocks
    const int tid = threadIdx.x;           // 256 = 4 waves
    const int lane = tid & 63, wave = tid >> 6;
    float a[8] = {0.f, 0.f, 0.f, 0.f, 0.f, 0.f, 0.f, 0.f};
    #pragma unroll
    for (int rep = 0; rep < 2; ++rep) {
        const int c = rep * 256 + tid;
        float m = 0.f;
        #pragma unroll
        for (int ht = 0; ht < 16; ++ht) m += pp[(b * 16 + ht) * 512 + c];
        #pragma unroll
        for (int e = 0; e < 8; ++e) a[e] += m * Wg[c * 8 + e];
    }
    #pragma unroll
    for (int e = 0; e < 8; ++e)
        #pragma unroll
        for (int off = 32; off; off >>= 1) a[e] += __shfl_xor(a[e], off, 64);
    __shared__ float red[4][8];
    if (lane == 0) {
        #pragma unroll
        for (int e = 0; e < 8; ++e) red[wave][e] = a[e];
    }
    __syncthreads();
    if (tid == 0) {
        float lg[8], mx = -1e30f;
        #pragma unroll
        for (int e = 0; e < 8; ++e) {
            lg[e] = (red[0][e] + red[1][e] + red[2][e] + red[3][e]) * (1.0f / 1024.0f) + bg[e];
            mx = fmaxf(mx, lg[e]);
        }
        float sum = 0.f;
        #pragma unroll
        for (int e = 0; e < 8; ++e) { lg[e] = expf(lg[e] - mx); sum += lg[e]; }
        float inv = 1.0f / sum;
        float best = -1.f; int i0 = 0;
        for (int j = 0; j < 8; ++j) { float w = lg[j] * inv; if (w > best) { best = w; i0 = j; } }
        float best2 = -1.f; int i1 = 0;
        for (int j = 0; j < 8; ++j) { if (j == i0) continue; float w = lg[j] * inv; if (w > best2) { best2 = w; i1 = j; } }
        float kb = kmod[b];
        tidx[b * 2] = i0; tidx[b * 2 + 1] = i1;
        scale[b * 2] = best * kb; scale[b * 2 + 1] = best2 * kb;
    }
}

// ---------- 3. GEMM1: 128x128 tile, BK=64, DOUBLE-buffer + 2-deep counted-vmcnt
// (R10 gemm2 schedule), XOR-swizzled LDS. hT = bf16(gelu(W1t[e]@xT[b]+b1)*scale)
// XCD swizzle: logical chunk of 128 blocks = pairs (2b,2b+1) -> XCD b writes hT[b].
__global__ __launch_bounds__(256, 2) void gemm1_kernel(
    const bf16_t* __restrict__ W1t, const bf16_t* __restrict__ xT,
    const float* __restrict__ b1, const int* __restrict__ tidx,
    const float* __restrict__ scale, bf16_t* __restrict__ hT) {
    // 64 KiB: stage st at st*16384: A[128x64]@+0, B[128x64]@+8192.
    // Epilogue buffer 128x136 (17408 el) aliases smem[0..] after the loop.
    __shared__ bf16_t smem[32768];
    const int bid = xcd_swz(blockIdx.x, 1024);
    const int pair = bid >> 6, rem = bid & 63;
    const int b = pair >> 1, slot = pair & 1;
    const int e = tidx[pair];
    const float s = scale[pair];
    const int d0 = (rem >> 3) * 128, n0 = (rem & 7) * 128;
    const int tid = threadIdx.x;
    const int lane = tid & 63, wave = tid >> 6;
    const int wm = (wave & 1) * 64, wn = (wave >> 1) * 64;
    const int lrow = lane & 15, quad = lane >> 4;

    const bf16_t* gA = W1t + (size_t)e * 524288 + (size_t)d0 * 512;
    const bf16_t* gB = xT + (size_t)b * 524288 + (size_t)n0 * 512;

    f32x4 acc[4][4];
    #pragma unroll
    for (int i = 0; i < 4; ++i)
        #pragma unroll
        for (int j = 0; j < 4; ++j) acc[i][j] = (f32x4){0.f, 0.f, 0.f, 0.f};

    auto stage = [&](int st, int it) {           // 8 GLDS / thread
        const int k0 = it * 64;
        bf16_t* dst = smem + st * 16384;
        #pragma unroll
        for (int p = 0; p < 4; ++p) {
            const int row = p * 32 + (tid >> 3);
            const int cg = ((tid & 7) ^ (row & 7)) * 8;
            GLDS(gA + (size_t)row * 512 + k0 + cg, dst + (p * 256 + tid) * 8);
            GLDS(gB + (size_t)row * 512 + k0 + cg, dst + 8192 + (p * 256 + tid) * 8);
        }
    };

    // prologue: 2 K-tiles in flight (16 outstanding loads/wave)
    stage(0, 0);
    stage(1, 1);

    for (int it = 0; it < 8; ++it) {
        const int cur = it & 1;
        if (it < 7) {
            asm volatile("s_waitcnt vmcnt(8)" ::: "memory");   // tile it landed; it+1 in flight
        } else {
            asm volatile("s_waitcnt vmcnt(0)" ::: "memory");   // tail
        }
        __builtin_amdgcn_s_barrier();            // tile it fully in LDS for all waves
        const bf16_t* cA = smem + cur * 16384;
        const bf16_t* cB = cA + 8192;
        #pragma unroll
        for (int kh = 0; kh < 2; ++kh) {
            const int swz = ((kh * 4 + quad) ^ (lrow & 7)) * 8;
            bf16x8 af[4], bfr[4];
            #pragma unroll
            for (int i = 0; i < 4; ++i) {
                af[i]  = *(const bf16x8*)&cA[(wm + i * 16 + lrow) * 64 + swz];
                bfr[i] = *(const bf16x8*)&cB[(wn + i * 16 + lrow) * 64 + swz];
            }
            #pragma unroll
            for (int i = 0; i < 4; ++i)
                #pragma unroll
                for (int j = 0; j < 4; ++j)
                    acc[i][j] = __builtin_amdgcn_mfma_f32_16x16x32_bf16(af[i], bfr[j], acc[i][j], 0, 0, 0);
        }
        __builtin_amdgcn_s_barrier();            // all waves done reading buf[cur]
        if (it < 6) stage(cur, it + 2);          // overwrite buf[cur] for tile it+2
    }

    // epilogue: all waves write all frags (one barrier), then coalesced 16B stores
    bf16_t* hTb = hT + (size_t)b * 2097152 + slot * 1024;
    #pragma unroll
    for (int i = 0; i < 4; ++i) {
        const int d_l = wm + i * 16 + quad * 4;
        const float4 bb = *(const float4*)(b1 + e * 1024 + d0 + d_l);
        #pragma unroll
        for (int j = 0; j < 4; ++j) {
            const int hw_l = wn + j * 16 + lrow;
            f32x4 a = acc[i][j];
            bf16x4 o = { (bf16_t)(gelu_fast(a[0] + bb.x) * s),
                         (bf16_t)(gelu_fast(a[1] + bb.y) * s),
                         (bf16_t)(gelu_fast(a[2] + bb.z) * s),
                         (bf16_t)(gelu_fast(a[3] + bb.w) * s) };
            *(bf16x4*)&smem[hw_l * 136 + d_l] = o;
        }
    }
    __syncthreads();
    #pragma unroll
    for (int q = 0; q < 8; ++q) {
        const int idx = q * 256 + tid;       // 2048 chunks = 128 rows x 16
        const int row = idx >> 4, c16 = idx & 15;
        bf16x8 v = *(const bf16x8*)&smem[row * 136 + c16 * 8];
        *(bf16x8*)(hTb + (size_t)(n0 + row) * 2048 + d0 + c16 * 8) = v;
    }
}

// ---------- 4. GEMM2: operand-swapped (A=hT, B=W2t) -> D[hw][c]; c64 x hw128 tile,
// BK=64, dbuf, grid 512 (2 blk/CU). out = x + D + s0*b2[e0] + s1*b2[e1], float4 stores.
// R10-proven: 2-deep counted-vmcnt (vmcnt(6) steady, vmcnt(0) tail), x prefetch.
__global__ __launch_bounds__(256, 2) void gemm2_kernel(
    const bf16_t* __restrict__ W2t, const bf16_t* __restrict__ hT,
    const float* __restrict__ b2, const int* __restrict__ tidx,
    const float* __restrict__ scale, const float* __restrict__ x,
    float* __restrict__ out) {
    __shared__ bf16_t smem[24576];   // 2 stages x (A hT[128x64]@0 + B W2t[64x64]@8192)
    const int bid = xcd_swz(blockIdx.x, 512);
    const int b = bid >> 6, rem = bid & 63;      // grid = 8 * 64 = 512
    const int c0 = (rem >> 3) * 64, hw0 = (rem & 7) * 128;
    const int e0 = tidx[b * 2], e1 = tidx[b * 2 + 1];
    const float s0 = scale[b * 2], s1 = scale[b * 2 + 1];
    const int tid = threadIdx.x;
    const int lane = tid & 63, wave = tid >> 6;
    const int wm = (wave & 1) * 64;              // hw offset (M)
    const int wc = (wave >> 1) * 32;             // c offset (N)
    const int lrow = lane & 15, quad = lane >> 4;

    const bf16_t* hTb = hT + (size_t)b * 2097152 + (size_t)hw0 * 2048;
    const bf16_t* B0 = W2t + (size_t)e0 * 524288 + (size_t)c0 * 1024;
    const bf16_t* B1 = W2t + (size_t)e1 * 524288 + (size_t)c0 * 1024;

    // prefetch residual x: 8 float4/thread (issued before any vmcnt asm, so
    // they drain with tile-0's wait; hides the old serial epilogue tail)
    float4 xr[2][4];
    #pragma unroll
    for (int j = 0; j < 2; ++j) {
        const int c = c0 + wc + j * 16 + lrow;
        #pragma unroll
        for (int i = 0; i < 4; ++i) {
            const int hw = hw0 + wm + i * 16 + quad * 4;
            xr[j][i] = *(const float4*)(x + ((size_t)(b * 512 + c)) * 1024 + hw);
        }
    }

    f32x4 acc[4][2];
    #pragma unroll
    for (int i = 0; i < 4; ++i)
        #pragma unroll
        for (int j = 0; j < 2; ++j) acc[i][j] = (f32x4){0.f, 0.f, 0.f, 0.f};

    auto stage = [&](int st, int it) {           // 6 GLDS / thread
        const int k0 = it * 64;
        bf16_t* dst = smem + st * 12288;
        #pragma unroll
        for (int p = 0; p < 4; ++p) {            // A: hT 128 hw-rows
            const int row = p * 32 + (tid >> 3);
            const int cg = ((tid & 7) ^ (row & 7)) * 8;
            GLDS(hTb + (size_t)row * 2048 + k0 + cg, dst + (p * 256 + tid) * 8);
        }
        const bf16_t* gB = ((it < 16) ? B0 : B1) + (k0 & 1023);
        #pragma unroll
        for (int p = 0; p < 2; ++p) {            // B: W2t 64 c-rows
            const int row = p * 32 + (tid >> 3);
            const int cg = ((tid & 7) ^ (row & 7)) * 8;
            GLDS(gB + (size_t)row * 1024 + cg, dst + 8192 + (p * 256 + tid) * 8);
        }
    };

    // prologue: 2 tiles in flight (12 outstanding loads + 8 x-prefetch)
    stage(0, 0);
    stage(1, 1);

    for (int it = 0; it < 32; ++it) {
        const int cur = it & 1;
        if (it < 31) {
            asm volatile("s_waitcnt vmcnt(6)" ::: "memory");   // tile it landed; it+1 in flight
        } else {
            asm volatile("s_waitcnt vmcnt(0)" ::: "memory");   // tail: drain tile 31
        }
        __builtin_amdgcn_s_barrier();            // all waves' tile-it slices in LDS
        const bf16_t* cA = smem + cur * 12288;
        const bf16_t* cB = cA + 8192;
        #pragma unroll
        for (int kh = 0; kh < 2; ++kh) {
            const int swz = ((kh * 4 + quad) ^ (lrow & 7)) * 8;
            bf16x8 af[4], bfr[2];
            #pragma unroll
            for (int i = 0; i < 4; ++i)
                af[i] = *(const bf16x8*)&cA[(wm + i * 16 + lrow) * 64 + swz];
            #pragma unroll
            for (int j = 0; j < 2; ++j)
                bfr[j] = *(const bf16x8*)&cB[(wc + j * 16 + lrow) * 64 + swz];
            #pragma unroll
            for (int i = 0; i < 4; ++i)
                #pragma unroll
                for (int j = 0; j < 2; ++j)
                    acc[i][j] = __builtin_amdgcn_mfma_f32_16x16x32_bf16(af[i], bfr[j], acc[i][j], 0, 0, 0);
        }
        __builtin_amdgcn_s_barrier();            // all waves done reading buf[cur]
        if (it < 30) stage(cur, it + 2);         // overwrite buf[cur] for tile it+2
    }

    // epilogue: lane f32x4 = 4 consecutive hw at one c -> fully-coalesced float4
    #pragma unroll
    for (int j = 0; j < 2; ++j) {
        const int c = c0 + wc + j * 16 + lrow;
        const float bias = s0 * b2[e0 * 512 + c] + s1 * b2[e1 * 512 + c];
        #pragma unroll
        for (int i = 0; i < 4; ++i) {
            const int hw = hw0 + wm + i * 16 + quad * 4;
            const size_t o = ((size_t)(b * 512 + c)) * 1024 + hw;
            const float4 xv = xr[j][i];
            float4 ov = { acc[i][j][0] + xv.x + bias, acc[i][j][1] + xv.y + bias,
                          acc[i][j][2] + xv.z + bias, acc[i][j][3] + xv.w + bias };
            *(float4*)(out + o) = ov;
        }
    }
}

extern "C" void kernel_launch(void* const* d_in, const int* in_sizes, int n_in,
                              void* d_out, int out_size, void* d_ws, size_t ws_size,
                              hipStream_t stream) {
    const float* x    = (const float*)d_in[0];
    const float* kmod = (const float*)d_in[1];
    const float* Wg   = (const float*)d_in[2];
    const float* bg   = (const float*)d_in[3];
    const float* W1   = (const float*)d_in[4];
    const float* b1   = (const float*)d_in[5];
    const float* W2   = (const float*)d_in[6];
    const float* b2   = (const float*)d_in[7];
    float* out = (float*)d_out;

    char* ws = (char*)d_ws;
    int*   tix  = (int*)ws;
    float* scl  = (float*)(ws + 64);
    bf16_t* xT  = (bf16_t*)(ws + 32768);
    bf16_t* W1t = (bf16_t*)(ws + 32768 + (size_t)8388608);
    bf16_t* W2t = (bf16_t*)(ws + 32768 + (size_t)2 * 8388608);
    bf16_t* hT  = (bf16_t*)(ws + 32768 + (size_t)3 * 8388608);
    float* pp   = (float*)hT;   // gate partials; dead before gemm1 writes hT

    transpose_cvt_all<<<3072, 256, 0, stream>>>(x, W1, W2, xT, W1t, W2t, pp);
    gate_kernel<<<8, 256, 0, stream>>>(pp, Wg, bg, kmod, tix, scl);
    gemm1_kernel<<<1024, 256, 0, stream>>>(W1t, xT, b1, tix, scl, hT);   // 16 pairs x 64
    gemm2_kernel<<<512, 256, 0, stream>>>(W2t, hT, b2, tix, scl, x, out); // 8 x 64
}